// Round 2
// baseline (284.076 us; speedup 1.0000x reference)
//
#include <hip/hip_runtime.h>

// B=32, C=256, H=64, W=64. Positions = 131072. Channel stride = 4096 floats.
// R1 design: 8-way C-split (32 ch/thread) x float4 over 4 consecutive
// positions. 1024 blocks x 256 threads = 4 blocks/CU (16 waves/CU) vs R0's 2.
// Per-instruction load width 16 B/lane. LDS combine of the 8 chunk-partials.

#define BB    32
#define CC    256
#define HH    64
#define WW    64
#define HWSZ  (HH * WW)           // 4096
#define NPOS  (BB * HWSZ)         // 131072
#define CSPLIT 8
#define CPER  (CC / CSPLIT)       // 32 channels per thread
#define PGPB  32                  // float4 position-groups per block
#define POSPB (PGPB * 4)          // 128 positions per block
#define SIM_EPS 1e-8f

__global__ __launch_bounds__(256, 4) void
sim_reduce_kernel(const float* __restrict__ u,
                  const float* __restrict__ m,
                  const int* __restrict__ mask,
                  double* __restrict__ ws)
{
    __shared__ float lds_num[CSPLIT * POSPB];   // 4 KB each
    __shared__ float lds_uu [CSPLIT * POSPB];
    __shared__ float lds_mm [CSPLIT * POSPB];

    const int tid    = threadIdx.x;
    const int posgrp = tid & (PGPB - 1);        // fast dim: contiguous 16 B segs
    const int cchunk = tid >> 5;                // 0..7

    const int p0 = blockIdx.x * POSPB + posgrp * 4;  // 128 positions/block => b const
    const int b  = p0 >> 12;
    const int hw = p0 & (HWSZ - 1);

    const size_t base = (size_t)b * CC * HWSZ + (size_t)cchunk * CPER * HWSZ + hw;
    const float4* up = (const float4*)(u + base);
    const float4* mp = (const float4*)(m + base);

    float4 num = {0.f, 0.f, 0.f, 0.f};
    float4 uu  = {0.f, 0.f, 0.f, 0.f};
    float4 mm  = {0.f, 0.f, 0.f, 0.f};

#pragma unroll 8
    for (int c = 0; c < CPER; ++c) {
        const float4 a = up[(size_t)c * (HWSZ / 4)];
        const float4 v = mp[(size_t)c * (HWSZ / 4)];
        num.x = fmaf(a.x, v.x, num.x); num.y = fmaf(a.y, v.y, num.y);
        num.z = fmaf(a.z, v.z, num.z); num.w = fmaf(a.w, v.w, num.w);
        uu.x  = fmaf(a.x, a.x, uu.x);  uu.y  = fmaf(a.y, a.y, uu.y);
        uu.z  = fmaf(a.z, a.z, uu.z);  uu.w  = fmaf(a.w, a.w, uu.w);
        mm.x  = fmaf(v.x, v.x, mm.x);  mm.y  = fmaf(v.y, v.y, mm.y);
        mm.z  = fmaf(v.z, v.z, mm.z);  mm.w  = fmaf(v.w, v.w, mm.w);
    }

    // b128 LDS writes: float layout lds[cchunk][posgrp*4 + j]
    ((float4*)lds_num)[cchunk * PGPB + posgrp] = num;
    ((float4*)lds_uu )[cchunk * PGPB + posgrp] = uu;
    ((float4*)lds_mm )[cchunk * PGPB + posgrp] = mm;
    __syncthreads();

    double sd = 0.0, md = 0.0;
    if (tid < POSPB) {
        float n = 0.f, su = 0.f, sm = 0.f;
#pragma unroll
        for (int cc = 0; cc < CSPLIT; ++cc) {       // stride-1 across lanes: no conflicts
            n  += lds_num[cc * POSPB + tid];
            su += lds_uu [cc * POSPB + tid];
            sm += lds_mm [cc * POSPB + tid];
        }
        const float denom = fmaxf(sqrtf(su), SIM_EPS) * fmaxf(sqrtf(sm), SIM_EPS);
        const float sim   = n / denom;
        const int   mk    = (mask[blockIdx.x * POSPB + tid] != 0) ? 1 : 0;
        sd = mk ? (double)sim : 0.0;
        md = (double)mk;
    }

    // Block reduction over 4 waves (upper half contributes zeros).
#pragma unroll
    for (int off = 32; off > 0; off >>= 1) {
        sd += __shfl_down(sd, off, 64);
        md += __shfl_down(md, off, 64);
    }

    __shared__ double red_s[4];
    __shared__ double red_m[4];
    const int wave = tid >> 6;
    const int lane = tid & 63;
    if (lane == 0) { red_s[wave] = sd; red_m[wave] = md; }
    __syncthreads();

    if (tid == 0) {
        const double ts = red_s[0] + red_s[1] + red_s[2] + red_s[3];
        const double tm = red_m[0] + red_m[1] + red_m[2] + red_m[3];
        atomicAdd(&ws[0], ts);
        atomicAdd(&ws[1], tm);
    }
}

__global__ void finalize_kernel(const double* __restrict__ ws,
                                float* __restrict__ out)
{
    out[0] = (float)(ws[0] / ws[1]);
}

extern "C" void kernel_launch(void* const* d_in, const int* in_sizes, int n_in,
                              void* d_out, int out_size, void* d_ws, size_t ws_size,
                              hipStream_t stream)
{
    const float* u    = (const float*)d_in[0];
    const float* m    = (const float*)d_in[1];
    const int*   mask = (const int*)d_in[2];
    float*  out = (float*)d_out;
    double* ws  = (double*)d_ws;

    hipMemsetAsync(d_ws, 0, 2 * sizeof(double), stream);

    sim_reduce_kernel<<<NPOS / POSPB, 256, 0, stream>>>(u, m, mask, ws);
    finalize_kernel<<<1, 1, 0, stream>>>(ws, out);
}

// Round 3
// 282.851 us; speedup vs baseline: 1.0043x; 1.0043x over previous
//
#include <hip/hip_runtime.h>

// B=32, C=256, H=64, W=64. Positions = 131072. Channel stride = 4096 floats.
// R2 design: force memory-level parallelism. Each thread: 16 channels x
// 4 consecutive positions, ALL 32 float4 loads staged into explicit register
// arrays before compute (32 KB in flight per wave). R1 showed the compiler
// (VGPR=36) kept only ~4 loads in flight -> latency-bound at 1.25 TB/s.

#define BB    32
#define CC    256
#define HH    64
#define WW    64
#define HWSZ  (HH * WW)           // 4096
#define NPOS  (BB * HWSZ)         // 131072
#define CSPLIT 16
#define CPER  (CC / CSPLIT)       // 16 channels per thread
#define PGPB  16                  // float4 position-groups per block
#define POSPB (PGPB * 4)          // 64 positions per block
#define SIM_EPS 1e-8f

__global__ __launch_bounds__(256) void
sim_reduce_kernel(const float* __restrict__ u,
                  const float* __restrict__ m,
                  const int* __restrict__ mask,
                  double* __restrict__ ws)
{
    __shared__ float lds_num[CSPLIT * POSPB];   // 4 KB each
    __shared__ float lds_uu [CSPLIT * POSPB];
    __shared__ float lds_mm [CSPLIT * POSPB];

    const int tid    = threadIdx.x;
    const int posgrp = tid & (PGPB - 1);
    const int cchunk = tid >> 4;                // 0..15

    const int p0 = blockIdx.x * POSPB + posgrp * 4;  // 64 positions/block
    const int b  = p0 >> 12;
    const int hw = p0 & (HWSZ - 1);

    const size_t base = (size_t)b * CC * HWSZ + (size_t)cchunk * CPER * HWSZ + hw;
    const float4* up = (const float4*)(u + base);
    const float4* mp = (const float4*)(m + base);

    // Stage ALL loads into registers first: 32 x 16 B in flight per lane.
    float4 a[CPER], v[CPER];
#pragma unroll
    for (int c = 0; c < CPER; ++c) a[c] = up[(size_t)c * (HWSZ / 4)];
#pragma unroll
    for (int c = 0; c < CPER; ++c) v[c] = mp[(size_t)c * (HWSZ / 4)];

    float4 num = {0.f, 0.f, 0.f, 0.f};
    float4 uu  = {0.f, 0.f, 0.f, 0.f};
    float4 mm  = {0.f, 0.f, 0.f, 0.f};
#pragma unroll
    for (int c = 0; c < CPER; ++c) {
        num.x = fmaf(a[c].x, v[c].x, num.x); num.y = fmaf(a[c].y, v[c].y, num.y);
        num.z = fmaf(a[c].z, v[c].z, num.z); num.w = fmaf(a[c].w, v[c].w, num.w);
        uu.x  = fmaf(a[c].x, a[c].x, uu.x);  uu.y  = fmaf(a[c].y, a[c].y, uu.y);
        uu.z  = fmaf(a[c].z, a[c].z, uu.z);  uu.w  = fmaf(a[c].w, a[c].w, uu.w);
        mm.x  = fmaf(v[c].x, v[c].x, mm.x);  mm.y  = fmaf(v[c].y, v[c].y, mm.y);
        mm.z  = fmaf(v[c].z, v[c].z, mm.z);  mm.w  = fmaf(v[c].w, v[c].w, mm.w);
    }

    ((float4*)lds_num)[cchunk * PGPB + posgrp] = num;
    ((float4*)lds_uu )[cchunk * PGPB + posgrp] = uu;
    ((float4*)lds_mm )[cchunk * PGPB + posgrp] = mm;
    __syncthreads();

    if (tid < POSPB) {                           // exactly wave 0
        float n = 0.f, su = 0.f, sm = 0.f;
#pragma unroll
        for (int cc = 0; cc < CSPLIT; ++cc) {    // stride-1 across lanes
            n  += lds_num[cc * POSPB + tid];
            su += lds_uu [cc * POSPB + tid];
            sm += lds_mm [cc * POSPB + tid];
        }
        const float denom = fmaxf(sqrtf(su), SIM_EPS) * fmaxf(sqrtf(sm), SIM_EPS);
        const float sim   = n / denom;
        const int   mk    = (mask[blockIdx.x * POSPB + tid] != 0) ? 1 : 0;
        double sd = mk ? (double)sim : 0.0;
        double md = (double)mk;
#pragma unroll
        for (int off = 32; off > 0; off >>= 1) {
            sd += __shfl_down(sd, off, 64);
            md += __shfl_down(md, off, 64);
        }
        if (tid == 0) {
            atomicAdd(&ws[0], sd);
            atomicAdd(&ws[1], md);
        }
    }
}

__global__ void finalize_kernel(const double* __restrict__ ws,
                                float* __restrict__ out)
{
    out[0] = (float)(ws[0] / ws[1]);
}

extern "C" void kernel_launch(void* const* d_in, const int* in_sizes, int n_in,
                              void* d_out, int out_size, void* d_ws, size_t ws_size,
                              hipStream_t stream)
{
    const float* u    = (const float*)d_in[0];
    const float* m    = (const float*)d_in[1];
    const int*   mask = (const int*)d_in[2];
    float*  out = (float*)d_out;
    double* ws  = (double*)d_ws;

    hipMemsetAsync(d_ws, 0, 2 * sizeof(double), stream);

    sim_reduce_kernel<<<NPOS / POSPB, 256, 0, stream>>>(u, m, mask, ws);
    finalize_kernel<<<1, 1, 0, stream>>>(ws, out);
}